// Round 1
// baseline (543.155 us; speedup 1.0000x reference)
//
#include <hip/hip_runtime.h>

// SAGE layer: out = relu(x @ W_self + (segment_sum(x[src], dst)/max(deg,1)) @ W_neigh + b)
// Phase 1: edge-parallel atomic scatter of x rows into d_out (summed) + deg histogram in d_ws.
// Phase 2: wave-per-row fused dual-GEMM (K=64 each) with W in LDS, deg-normalize, bias, relu.

constexpr int F = 64;  // IN_FEATS == N_CLASSES == 64

__global__ __launch_bounds__(256) void sage_scatter(
    const float* __restrict__ x,
    const int* __restrict__ src,
    const int* __restrict__ dst,
    float* __restrict__ summed,
    float* __restrict__ deg,
    int n_edges)
{
    long tid = (long)blockIdx.x * 256 + threadIdx.x;
    int e = (int)(tid >> 6);          // one wave (64 lanes) per edge
    if (e >= n_edges) return;
    int f = threadIdx.x & 63;
    int s = src[e];
    int d = dst[e];
    float v = x[(long)s * F + f];
    atomicAdd(&summed[(long)d * F + f], v);
    if (f == 0) atomicAdd(&deg[d], 1.0f);
}

__global__ __launch_bounds__(256) void sage_gemm(
    const float* __restrict__ x,
    const float* __restrict__ Ws,
    const float* __restrict__ Wn,
    const float* __restrict__ b,
    const float* __restrict__ deg,
    float* inout,       // summed on input, h on output (intentionally aliased)
    int num_dst)
{
    __shared__ float Wl[2 * F * F];  // 32 KB: W_self then W_neigh, row-major [k][j]
    for (int i = threadIdx.x; i < F * F; i += 256) {
        Wl[i]         = Ws[i];
        Wl[F * F + i] = Wn[i];
    }
    __syncthreads();

    int lane = threadIdx.x & 63;
    int r = (blockIdx.x * 256 + threadIdx.x) >> 6;  // one wave per output row
    if (r >= num_dst) return;

    float bias = b[lane];
    float xv = x[(long)r * F + lane];
    float sv = inout[(long)r * F + lane];
    float dg = deg[r];
    float hv = sv / fmaxf(dg, 1.0f);

    float acc = bias;
#pragma unroll
    for (int k = 0; k < F; ++k) {
        float a = __shfl(xv, k);   // broadcast x[r][k]
        float c = __shfl(hv, k);   // broadcast h_neigh[r][k]
        acc += a * Wl[k * F + lane];         // lane j: W_self[k][j]
        acc += c * Wl[(F + k) * F + lane];   // lane j: W_neigh[k][j]
    }
    inout[(long)r * F + lane] = fmaxf(acc, 0.0f);
}

extern "C" void kernel_launch(void* const* d_in, const int* in_sizes, int n_in,
                              void* d_out, int out_size, void* d_ws, size_t ws_size,
                              hipStream_t stream) {
    const float* x  = (const float*)d_in[0];
    const float* Ws = (const float*)d_in[1];
    const float* Wn = (const float*)d_in[2];
    const float* b  = (const float*)d_in[3];
    const int* src  = (const int*)d_in[4];
    const int* dst  = (const int*)d_in[5];
    int n_edges = in_sizes[4];
    int num_dst = out_size / F;

    float* out = (float*)d_out;   // doubles as the segment-sum accumulator
    float* deg = (float*)d_ws;    // num_dst floats

    hipMemsetAsync(d_out, 0, (size_t)out_size * sizeof(float), stream);
    hipMemsetAsync(deg, 0, (size_t)num_dst * sizeof(float), stream);

    long total_threads = (long)n_edges * 64;
    int blocks1 = (int)((total_threads + 255) / 256);
    sage_scatter<<<blocks1, 256, 0, stream>>>(x, src, dst, out, deg, n_edges);

    int blocks2 = (num_dst + 3) / 4;  // 4 waves per block, wave per row
    sage_gemm<<<blocks2, 256, 0, stream>>>(x, Ws, Wn, b, deg, out, num_dst);
}

// Round 2
// 276.670 us; speedup vs baseline: 1.9632x; 1.9632x over previous
//
#include <hip/hip_runtime.h>

// SAGE layer: out = relu(x @ W_self + (segment_sum(x[src], dst)/max(deg,1)) @ W_neigh + b)
//
// Main path (needs ~31 MB ws):
//   1. hist: int deg histogram over dst (1M int atomics)
//   2-4. two-level exclusive scan -> row_start, cursor
//   5. fill: CSR edge list via cursor atomics
//   6. aggregate: wave-per-row gather-sum of x rows (LLC-resident), normalized -> h
//   7. gemm: bf16 MFMA, A=[x|h] (K=128), W=[Ws;Wn], bias+relu epilogue
// Fallback (small ws): R0 atomic scatter + the same MFMA gemm (divide-by-deg in staging).

constexpr int F = 64;
constexpr int LDK = 136;  // 128 k + 8 pad (bf16 elems); row stride 272 B, 16B-aligned

typedef __attribute__((ext_vector_type(8))) short short8;
typedef __attribute__((ext_vector_type(4))) float float4v;

__device__ inline unsigned short f2bf(float f) {
    union { float f; unsigned u; } c; c.f = f;
    unsigned u = c.u;
    return (unsigned short)((u + 0x7FFFu + ((u >> 16) & 1u)) >> 16);  // RNE
}

// ---------------- CSR build ----------------

__global__ __launch_bounds__(256) void k_hist(const int* __restrict__ dst, int* __restrict__ deg, int n_edges) {
    for (int e = blockIdx.x * 256 + threadIdx.x; e < n_edges; e += gridDim.x * 256)
        atomicAdd(&deg[dst[e]], 1);
}

__global__ __launch_bounds__(256) void k_scan_part(const int* __restrict__ deg, int* __restrict__ row_start,
                                                   int* __restrict__ bsum, int n) {
    __shared__ int buf[256];
    int t = threadIdx.x;
    int i = blockIdx.x * 256 + t;
    int v = (i < n) ? deg[i] : 0;
    buf[t] = v; __syncthreads();
    for (int off = 1; off < 256; off <<= 1) {
        int tv = (t >= off) ? buf[t - off] : 0;
        __syncthreads();
        buf[t] += tv;
        __syncthreads();
    }
    if (i < n) row_start[i] = buf[t] - v;      // exclusive within block
    if (t == 255) bsum[blockIdx.x] = buf[255]; // block total
}

__global__ __launch_bounds__(512) void k_scan_top(int* __restrict__ bsum, int nb) {
    __shared__ int buf[512];
    int t = threadIdx.x;
    int v = (t < nb) ? bsum[t] : 0;
    buf[t] = v; __syncthreads();
    for (int off = 1; off < 512; off <<= 1) {
        int tv = (t >= off) ? buf[t - off] : 0;
        __syncthreads();
        buf[t] += tv;
        __syncthreads();
    }
    if (t < nb) bsum[t] = buf[t] - v;          // exclusive block offsets
}

__global__ __launch_bounds__(256) void k_scan_add(int* __restrict__ row_start, const int* __restrict__ bsum,
                                                  int* __restrict__ cursor, int n, int n_edges) {
    int i = blockIdx.x * 256 + threadIdx.x;
    if (i < n) {
        int v = row_start[i] + bsum[i >> 8];
        row_start[i] = v;
        cursor[i] = v;
    }
    if (i == 0) row_start[n] = n_edges;
}

__global__ __launch_bounds__(256) void k_fill(const int* __restrict__ src, const int* __restrict__ dst,
                                              int* __restrict__ cursor, int* __restrict__ csr, int n_edges) {
    for (int e = blockIdx.x * 256 + threadIdx.x; e < n_edges; e += gridDim.x * 256) {
        int p = atomicAdd(&cursor[dst[e]], 1);
        csr[p] = src[e];
    }
}

// ---------------- aggregate: wave per dst row ----------------

__global__ __launch_bounds__(256) void k_aggregate(const float* __restrict__ x,
                                                   const int* __restrict__ row_start,
                                                   const int* __restrict__ csr,
                                                   float* __restrict__ h, int num_dst) {
    int lane = threadIdx.x & 63;
    int r = (blockIdx.x * 256 + threadIdx.x) >> 6;
    if (r >= num_dst) return;
    int s0 = row_start[r], s1 = row_start[r + 1];
    float a0 = 0.0f, a1 = 0.0f;
    for (int base = s0; base < s1; base += 64) {
        int sid = (base + lane < s1) ? csr[base + lane] : 0;
        int n = min(64, s1 - base);
        int i = 0;
        for (; i + 1 < n; i += 2) {
            int e0 = __shfl(sid, i);
            int e1 = __shfl(sid, i + 1);
            a0 += x[(long)e0 * F + lane];
            a1 += x[(long)e1 * F + lane];
        }
        if (i < n) a0 += x[(long)__shfl(sid, i) * F + lane];
    }
    float deg = (float)(s1 - s0);
    h[(long)r * F + lane] = (a0 + a1) / fmaxf(deg, 1.0f);
}

// ---------------- fallback scatter (R0) ----------------

__global__ __launch_bounds__(256) void k_scatter(const float* __restrict__ x, const int* __restrict__ src,
                                                 const int* __restrict__ dst, float* __restrict__ summed,
                                                 float* __restrict__ degf, int n_edges) {
    long tid = (long)blockIdx.x * 256 + threadIdx.x;
    int e = (int)(tid >> 6);
    if (e >= n_edges) return;
    int f = threadIdx.x & 63;
    int s = src[e], d = dst[e];
    atomicAdd(&summed[(long)d * F + f], x[(long)s * F + f]);
    if (f == 0) atomicAdd(&degf[d], 1.0f);
}

// ---------------- fused dual-GEMM, bf16 MFMA ----------------
// A = [x | h] (64 rows x K=128), W = [Ws; Wn] (128 x 64). 64x64 tile per block.

__global__ __launch_bounds__(256) void k_gemm_mfma(
    const float* __restrict__ x, const float* __restrict__ h,
    const float* __restrict__ degf,   // null -> h already normalized
    const float* __restrict__ Ws, const float* __restrict__ Wn,
    const float* __restrict__ b, float* __restrict__ out, int num_dst)
{
    __shared__ __align__(16) unsigned short Atile[64 * LDK];  // [row][k]
    __shared__ __align__(16) unsigned short Wt[64 * LDK];     // [n][k] (W transposed)
    int t = threadIdx.x;
    int row0 = blockIdx.x * 64;

    // stage W transposed to bf16
    for (int i = t; i < 128 * 64; i += 256) {
        int k = i >> 6, n = i & 63;
        float v = (k < 64) ? Ws[k * 64 + n] : Wn[(k - 64) * 64 + n];
        Wt[n * LDK + k] = f2bf(v);
    }
    // stage A = [x_row | h_row] to bf16 (float4 global reads)
    for (int i = t; i < 64 * 16; i += 256) {
        int r = i >> 4, c = (i & 15) * 4;
        int g = row0 + r;
        float4 xv = make_float4(0.f, 0.f, 0.f, 0.f);
        float4 hv = xv;
        float inv = 1.0f;
        if (g < num_dst) {
            xv = *(const float4*)&x[(long)g * F + c];
            hv = *(const float4*)&h[(long)g * F + c];
            if (degf) inv = 1.0f / fmaxf(degf[g], 1.0f);
        }
        unsigned short* ar = &Atile[r * LDK];
        ar[c + 0] = f2bf(xv.x); ar[c + 1] = f2bf(xv.y);
        ar[c + 2] = f2bf(xv.z); ar[c + 3] = f2bf(xv.w);
        ar[64 + c + 0] = f2bf(hv.x * inv); ar[64 + c + 1] = f2bf(hv.y * inv);
        ar[64 + c + 2] = f2bf(hv.z * inv); ar[64 + c + 3] = f2bf(hv.w * inv);
    }
    __syncthreads();

    int lane = t & 63;
    int wave = t >> 6;
    int m = lane & 15;        // A row within wave-tile / B col within n-tile
    int quad = lane >> 4;     // k-chunk selector (k = quad*8 + j)
    const unsigned short* arow = &Atile[(wave * 16 + m) * LDK + quad * 8];

    float4v acc[4];
#pragma unroll
    for (int nt = 0; nt < 4; ++nt) acc[nt] = (float4v){0.f, 0.f, 0.f, 0.f};

#pragma unroll
    for (int kb = 0; kb < 4; ++kb) {
        short8 a = *(const short8*)(arow + kb * 32);
#pragma unroll
        for (int nt = 0; nt < 4; ++nt) {
            short8 bf = *(const short8*)&Wt[(nt * 16 + m) * LDK + quad * 8 + kb * 32];
            acc[nt] = __builtin_amdgcn_mfma_f32_16x16x32_bf16(a, bf, acc[nt], 0, 0, 0);
        }
    }

    // epilogue: C/D layout col=lane&15, row=quad*4+reg
    int gr_base = row0 + wave * 16 + quad * 4;
#pragma unroll
    for (int nt = 0; nt < 4; ++nt) {
        int col = nt * 16 + m;
        float bias = b[col];
#pragma unroll
        for (int rg = 0; rg < 4; ++rg) {
            int g = gr_base + rg;
            if (g < num_dst) out[(long)g * F + col] = fmaxf(acc[nt][rg] + bias, 0.0f);
        }
    }
}

// ---------------- launch ----------------

extern "C" void kernel_launch(void* const* d_in, const int* in_sizes, int n_in,
                              void* d_out, int out_size, void* d_ws, size_t ws_size,
                              hipStream_t stream) {
    const float* x  = (const float*)d_in[0];
    const float* Ws = (const float*)d_in[1];
    const float* Wn = (const float*)d_in[2];
    const float* b  = (const float*)d_in[3];
    const int* src  = (const int*)d_in[4];
    const int* dst  = (const int*)d_in[5];
    int n_edges = in_sizes[4];
    int num_dst = out_size / F;
    float* out = (float*)d_out;

    // ws layout (ints/floats, 4B units)
    char* ws = (char*)d_ws;
    size_t off = 0;
    auto alloc = [&](size_t bytes) { char* p = ws + off; off = (off + bytes + 255) & ~(size_t)255; return p; };
    int*   deg       = (int*)alloc((size_t)num_dst * 4);
    int*   row_start = (int*)alloc((size_t)(num_dst + 1) * 4);
    int*   cursor    = (int*)alloc((size_t)num_dst * 4);
    int*   bsum      = (int*)alloc(1024 * 4);
    int*   csr       = (int*)alloc((size_t)n_edges * 4);
    float* h         = (float*)alloc((size_t)num_dst * F * 4);
    bool big_ws = (off <= ws_size);

    if (big_ws) {
        hipMemsetAsync(deg, 0, (size_t)num_dst * 4, stream);

        int gs = 2048;
        k_hist<<<gs, 256, 0, stream>>>(dst, deg, n_edges);

        int nb = (num_dst + 255) / 256;
        k_scan_part<<<nb, 256, 0, stream>>>(deg, row_start, bsum, num_dst);
        k_scan_top<<<1, 512, 0, stream>>>(bsum, nb);
        k_scan_add<<<nb, 256, 0, stream>>>(row_start, bsum, cursor, num_dst, n_edges);

        k_fill<<<gs, 256, 0, stream>>>(src, dst, cursor, csr, n_edges);

        k_aggregate<<<(num_dst + 3) / 4, 256, 0, stream>>>(x, row_start, csr, h, num_dst);

        k_gemm_mfma<<<(num_dst + 63) / 64, 256, 0, stream>>>(x, h, nullptr, Ws, Wn, b, out, num_dst);
    } else {
        // fallback: atomic scatter into d_out, deg(float) in ws
        float* degf = (float*)d_ws;
        hipMemsetAsync(d_out, 0, (size_t)out_size * sizeof(float), stream);
        hipMemsetAsync(degf, 0, (size_t)num_dst * sizeof(float), stream);
        long tt = (long)n_edges * 64;
        k_scatter<<<(int)((tt + 255) / 256), 256, 0, stream>>>(x, src, dst, out, degf, n_edges);
        k_gemm_mfma<<<(num_dst + 63) / 64, 256, 0, stream>>>(x, out, degf, Ws, Wn, b, out, num_dst);
    }
}